// Round 3
// baseline (1452.383 us; speedup 1.0000x reference)
//
#include <hip/hip_runtime.h>
#include <stdint.h>

#pragma clang fp contract(off)

#define B 8
#define N 65536
#define KC 64        // clusters
#define M 128        // neighbors per center (NPOINT/K*2)
#define S 64         // fps samples per group (NPOINT/K)
#define NITER 10
#define CHUNK 256
#define NCHUNK (N / CHUNK)   // 256
#define SUMCHUNK 2048        // points staged in LDS per pass in k_sum_divide

using u32 = unsigned int;
using u64 = unsigned long long;

// ---- exact fp32 helpers (no FMA contraction, fixed association) ----
__device__ __forceinline__ float sq3(float a, float b, float c) {
  return __fadd_rn(__fadd_rn(__fmul_rn(a, a), __fmul_rn(b, b)), __fmul_rn(c, c));
}
__device__ __forceinline__ float dot3(float x0, float x1, float x2,
                                      float c0, float c1, float c2) {
  return __fadd_rn(__fadd_rn(__fmul_rn(x0, c0), __fmul_rn(x1, c1)), __fmul_rn(x2, c2));
}
__device__ __forceinline__ float distf(float s2, float d2, float dt) {
  // (s2 + d2) - 2*dot   — matches reference op order
  return __fsub_rn(__fadd_rn(s2, d2), __fmul_rn(2.0f, dt));
}
// monotone float->uint key (total order preserving)
__device__ __forceinline__ u32 fkey(float f) {
  u32 u = __float_as_uint(f);
  return (u & 0x80000000u) ? ~u : (u | 0x80000000u);
}

// ---- kernels ----

__global__ void k_init_centers(const float* __restrict__ x, float* __restrict__ centers) {
  int i = blockIdx.x * blockDim.x + threadIdx.x;
  if (i >= B * KC * 3) return;
  int b = i / (KC * 3);
  int r = i % (KC * 3);
  centers[i] = x[(size_t)b * N * 3 + r];   // c = x[:, :K, :]
}

__global__ void k_assign(const float* __restrict__ x, const float* __restrict__ centers,
                         unsigned char* __restrict__ cl, int* __restrict__ hist) {
  __shared__ float cx[KC], cy[KC], cz[KC], d2s[KC];
  __shared__ int lh[KC];
  int b = blockIdx.x >> 8;
  int chunk = blockIdx.x & 255;
  int t = threadIdx.x;
  if (t < KC) {
    float a0 = centers[(b * KC + t) * 3 + 0];
    float a1 = centers[(b * KC + t) * 3 + 1];
    float a2 = centers[(b * KC + t) * 3 + 2];
    cx[t] = a0; cy[t] = a1; cz[t] = a2;
    d2s[t] = sq3(a0, a1, a2);
    lh[t] = 0;
  }
  __syncthreads();
  int n = chunk * CHUNK + t;
  size_t xb = ((size_t)b * N + n) * 3;
  float x0 = x[xb], x1 = x[xb + 1], x2 = x[xb + 2];
  float s2 = sq3(x0, x1, x2);
  float best = __int_as_float(0x7f800000);  // +inf
  int bi = 0;
  for (int k = 0; k < KC; ++k) {
    float dt = dot3(x0, x1, x2, cx[k], cy[k], cz[k]);
    float d = distf(s2, d2s[k], dt);
    if (d < best) { best = d; bi = k; }     // first-min tie-break == argmin
  }
  cl[(size_t)b * N + n] = (unsigned char)bi;
  atomicAdd(&lh[bi], 1);
  __syncthreads();
  if (t < KC) hist[((b * NCHUNK) + chunk) * KC + t] = lh[t];
}

__global__ void k_scan_chunks(const int* __restrict__ hist, int* __restrict__ chunkOff,
                              int* __restrict__ totals) {
  int gt = blockIdx.x * blockDim.x + threadIdx.x;
  if (gt >= B * KC) return;
  int b = gt >> 6, k = gt & 63;
  int run = 0;
  for (int c = 0; c < NCHUNK; ++c) {
    int idx = ((b * NCHUNK) + c) * KC + k;
    chunkOff[idx] = run;
    run += hist[idx];
  }
  totals[gt] = run;
}

__global__ void k_batch_prefix(const int* __restrict__ totals, int* __restrict__ kBase) {
  int b = threadIdx.x;
  if (b >= B) return;
  int base = 0;
  for (int k = 0; k < KC; ++k) { kBase[b * KC + k] = base; base += totals[b * KC + k]; }
}

// stable counting-sort scatter: writes point coords grouped by cluster, in
// increasing original index order within each cluster (matches np.add.at order)
__global__ void k_scatter(const float* __restrict__ x, const unsigned char* __restrict__ cl,
                          const int* __restrict__ chunkOff, const int* __restrict__ kBase,
                          float* __restrict__ sortedPts) {
  __shared__ unsigned char lcl[CHUNK];
  int b = blockIdx.x >> 8, chunk = blockIdx.x & 255, t = threadIdx.x;
  int n = chunk * CHUNK + t;
  lcl[t] = cl[(size_t)b * N + n];
  __syncthreads();
  int k = lcl[t];
  int rank = 0;
  for (int j = 0; j < t; ++j) rank += (lcl[j] == k);
  int pos = kBase[b * KC + k] + chunkOff[((b * NCHUNK) + chunk) * KC + k] + rank;
  size_t src = ((size_t)b * N + n) * 3;
  size_t dst = ((size_t)b * N + pos) * 3;
  sortedPts[dst]     = x[src];
  sortedPts[dst + 1] = x[src + 1];
  sortedPts[dst + 2] = x[src + 2];
}

// one block per (b,k): cooperative LDS staging, lane 0 does the strictly
// sequential fp32 sum in original index order (bit-identical to np.add.at)
__global__ void k_sum_divide(const float* __restrict__ sortedPts,
                             const int* __restrict__ kBase, const int* __restrict__ totals,
                             float* __restrict__ centers) {
  __shared__ float buf[3 * SUMCHUNK];
  int gt = blockIdx.x;         // b*KC + k
  int b = gt >> 6;
  int t = threadIdx.x;
  int off = kBase[gt], cnt = totals[gt];
  const float* sp = sortedPts + ((size_t)b * N + off) * 3;
  float sx = 0.f, sy = 0.f, sz = 0.f;
  for (int base = 0; base < cnt; base += SUMCHUNK) {
    int m = min(SUMCHUNK, cnt - base);
    int nf = m * 3;
    for (int i = t; i < nf; i += 256) buf[i] = sp[(size_t)base * 3 + i];
    __syncthreads();
    if (t == 0) {
#pragma unroll 4
      for (int i = 0; i < m; ++i) {
        sx = __fadd_rn(sx, buf[3 * i]);
        sy = __fadd_rn(sy, buf[3 * i + 1]);
        sz = __fadd_rn(sz, buf[3 * i + 2]);
      }
    }
    __syncthreads();
  }
  if (t == 0) {
    float fc = (float)cnt;
    centers[gt * 3 + 0] = __fdiv_rn(sx, fc);
    centers[gt * 3 + 1] = __fdiv_rn(sy, fc);
    centers[gt * 3 + 2] = __fdiv_rn(sz, fc);
  }
}

// exact top-M (smallest distance, lower-index tiebreak) per (b,center)
// via 4-round byte radix-select on monotone keys + exact (key,idx) sort.
__global__ void k_query_topk(const float* __restrict__ x, const float* __restrict__ centers,
                             float* __restrict__ neighbor) {
  __shared__ u32 hist[256];
  __shared__ u64 lessList[M];
  __shared__ u32 eqList[256];
  __shared__ u32 sPrefix;
  __shared__ int sNeed;
  __shared__ int cntLess, cntEq;
  __shared__ float sc0, sc1, sc2, sd2;

  int bk = blockIdx.x;      // b*KC + k
  int b = bk >> 6;
  int t = threadIdx.x;
  if (t == 0) {
    float c0 = centers[bk * 3], c1 = centers[bk * 3 + 1], c2 = centers[bk * 3 + 2];
    sc0 = c0; sc1 = c1; sc2 = c2; sd2 = sq3(c0, c1, c2);
    cntLess = 0; cntEq = 0;
  }
  __syncthreads();
  float c0 = sc0, c1 = sc1, c2 = sc2, d2 = sd2;
  const float* xb = x + (size_t)b * N * 3;

  u32 prefix = 0;
  int need = M;
  for (int r = 3; r >= 0; --r) {
    for (int i = t; i < 256; i += 256) hist[i] = 0;
    __syncthreads();
    int sh = r * 8;
    for (int n = t; n < N; n += 256) {
      float x0 = xb[n * 3], x1 = xb[n * 3 + 1], x2 = xb[n * 3 + 2];
      float d = distf(sq3(x0, x1, x2), d2, dot3(x0, x1, x2, c0, c1, c2));
      u32 key = fkey(d);
      bool ok = (r == 3) || ((key >> (sh + 8)) == (prefix >> (sh + 8)));
      if (ok) atomicAdd(&hist[(key >> sh) & 255u], 1u);
    }
    __syncthreads();
    if (t == 0) {
      int cum = 0;
      for (int bin = 0; bin < 256; ++bin) {
        int c = (int)hist[bin];
        if (cum + c >= need) { sPrefix = prefix | ((u32)bin << sh); sNeed = need - cum; break; }
        cum += c;
      }
    }
    __syncthreads();
    prefix = sPrefix; need = sNeed;
    __syncthreads();
  }
  u32 K128 = prefix;   // exact key of the M-th smallest distance

  for (int n = t; n < N; n += 256) {
    float x0 = xb[n * 3], x1 = xb[n * 3 + 1], x2 = xb[n * 3 + 2];
    float d = distf(sq3(x0, x1, x2), d2, dot3(x0, x1, x2, c0, c1, c2));
    u32 key = fkey(d);
    if (key < K128) {
      int p = atomicAdd(&cntLess, 1);
      if (p < M) lessList[p] = ((u64)key << 32) | (u32)n;   // p < M guaranteed
    } else if (key == K128) {
      int p = atomicAdd(&cntEq, 1);
      if (p < 256) eqList[p] = (u32)n;
    }
  }
  __syncthreads();
  int nl = cntLess;   // < M by construction
  int ne = cntEq;
  for (int i = t; i < M; i += 256) if (i >= nl) lessList[i] = ~0ull;
  for (int i = t; i < 256; i += 256) if (i >= ne) eqList[i] = 0xFFFFFFFFu;
  __syncthreads();

  // bitonic sort lessList[M] ascending by (key, idx)
  for (int ksz = 2; ksz <= M; ksz <<= 1) {
    for (int j = ksz >> 1; j > 0; j >>= 1) {
      if (t < M) {
        int ixj = t ^ j;
        if (ixj > t) {
          u64 a = lessList[t], bb = lessList[ixj];
          bool up = ((t & ksz) == 0);
          if (up ? (a > bb) : (a < bb)) { lessList[t] = bb; lessList[ixj] = a; }
        }
      }
      __syncthreads();
    }
  }
  // bitonic sort eqList[256] ascending by idx
  for (int ksz = 2; ksz <= 256; ksz <<= 1) {
    for (int j = ksz >> 1; j > 0; j >>= 1) {
      int ixj = t ^ j;
      if (ixj > t) {
        u32 a = eqList[t], bb = eqList[ixj];
        bool up = ((t & ksz) == 0);
        if (up ? (a > bb) : (a < bb)) { eqList[t] = bb; eqList[ixj] = a; }
      }
      __syncthreads();
    }
  }

  if (t < M) {
    int idx = (t < nl) ? (int)(lessList[t] & 0xFFFFFFFFu) : (int)eqList[t - nl];
    size_t src = ((size_t)b * N + idx) * 3;
    size_t dst = ((size_t)bk * M + t) * 3;
    neighbor[dst]     = x[src];
    neighbor[dst + 1] = x[src + 1];
    neighbor[dst + 2] = x[src + 2];
  }
}

__global__ void k_fps(const float* __restrict__ neighbor, const int* __restrict__ farthest0,
                      float* __restrict__ out) {
  __shared__ float px[M], py[M], pz[M];
  __shared__ float wv[2];
  __shared__ int wi[2];
  int bg = blockIdx.x;  // b*64 + g
  int b = bg >> 6, g = bg & 63;
  int t = threadIdx.x;  // 128 threads = M
  size_t src = ((size_t)bg * M + t) * 3;
  float mx = neighbor[src], my = neighbor[src + 1], mz = neighbor[src + 2];
  px[t] = mx; py[t] = my; pz[t] = mz;
  int far = farthest0[bg];
  float dist = 1e10f;
  __syncthreads();
  for (int s = 0; s < S; ++s) {
    // record current farthest (scan outputs OLD carry), then update
    if (t == far) {
      size_t dst = ((size_t)b * 4096 + g * 64 + s) * 3;
      out[dst] = mx; out[dst + 1] = my; out[dst + 2] = mz;
    }
    float cx = px[far], cy = py[far], cz = pz[far];
    float dx = __fsub_rn(mx, cx), dy = __fsub_rn(my, cy), dz = __fsub_rn(mz, cz);
    float d = sq3(dx, dy, dz);
    dist = fminf(dist, d);
    float v = dist;
    int i = t;
#pragma unroll
    for (int off = 1; off < 64; off <<= 1) {
      float ov = __shfl_xor(v, off);
      int oi = __shfl_xor(i, off);
      if (ov > v || (ov == v && oi < i)) { v = ov; i = oi; }
    }
    int wid = t >> 6;
    if ((t & 63) == 0) { wv[wid] = v; wi[wid] = i; }
    __syncthreads();
    float v0 = wv[0]; int i0 = wi[0];
    float v1 = wv[1]; int i1 = wi[1];
    far = (v1 > v0 || (v1 == v0 && i1 < i0)) ? i1 : i0;  // first-occurrence argmax
    __syncthreads();
  }
}

__global__ void k_copy_centers(const float* __restrict__ centers, float* __restrict__ out) {
  int i = blockIdx.x * blockDim.x + threadIdx.x;
  if (i < B * KC * 3) out[B * 4096 * 3 + i] = centers[i];
}

extern "C" void kernel_launch(void* const* d_in, const int* in_sizes, int n_in,
                              void* d_out, int out_size, void* d_ws, size_t ws_size,
                              hipStream_t stream) {
  const float* x = (const float*)d_in[0];
  const int* farthest0 = (const int*)d_in[1];
  float* out = (float*)d_out;

  char* w = (char*)d_ws;
  float* centers         = (float*)(w);                         // 6144 B
  int* totals            = (int*)(w + 8192);                    // 2048 B
  int* kBase             = (int*)(w + 16384);                   // 2048 B
  unsigned char* cl      = (unsigned char*)(w + 24576);         // 524288 B
  int* hist              = (int*)(w + 24576 + 524288);          // 524288 B
  int* chunkOff          = (int*)(w + 24576 + 2 * 524288);      // 524288 B
  float* sortedPts       = (float*)(w + 24576 + 3 * 524288);    // 6291456 B
  float* neighbor        = (float*)(w + 24576 + 3 * 524288 + 6291456); // 786432 B
  // total ws use ≈ 8.7 MB

  k_init_centers<<<6, 256, 0, stream>>>(x, centers);
  for (int it = 0; it < NITER; ++it) {
    k_assign<<<B * NCHUNK, 256, 0, stream>>>(x, centers, cl, hist);
    k_scan_chunks<<<2, 256, 0, stream>>>(hist, chunkOff, totals);
    k_batch_prefix<<<1, 64, 0, stream>>>(totals, kBase);
    k_scatter<<<B * NCHUNK, 256, 0, stream>>>(x, cl, chunkOff, kBase, sortedPts);
    k_sum_divide<<<B * KC, 256, 0, stream>>>(sortedPts, kBase, totals, centers);
  }
  k_query_topk<<<B * KC, 256, 0, stream>>>(x, centers, neighbor);
  k_fps<<<B * KC, M, 0, stream>>>(neighbor, farthest0, out);
  k_copy_centers<<<6, 256, 0, stream>>>(centers, out);
}

// Round 4
// 1428.945 us; speedup vs baseline: 1.0164x; 1.0164x over previous
//
#include <hip/hip_runtime.h>
#include <stdint.h>

#pragma clang fp contract(off)

#define B 8
#define N 65536
#define KC 64        // clusters
#define M 128        // neighbors per center (NPOINT/K*2)
#define S 64         // fps samples per group (NPOINT/K)
#define NITER 10
#define CHUNK 256
#define NCHUNK (N / CHUNK)   // 256
#define SUMCHUNK 2048        // points staged in LDS per pass in k_sum_divide

using u32 = unsigned int;
using u64 = unsigned long long;

// ---- exact fp32 helpers (no FMA contraction, fixed association) ----
__device__ __forceinline__ float sq3(float a, float b, float c) {
  return __fadd_rn(__fadd_rn(__fmul_rn(a, a), __fmul_rn(b, b)), __fmul_rn(c, c));
}
__device__ __forceinline__ float dot3(float x0, float x1, float x2,
                                      float c0, float c1, float c2) {
  return __fadd_rn(__fadd_rn(__fmul_rn(x0, c0), __fmul_rn(x1, c1)), __fmul_rn(x2, c2));
}
__device__ __forceinline__ float distf(float s2, float d2, float dt) {
  // (s2 + d2) - 2*dot   — matches reference op order
  return __fsub_rn(__fadd_rn(s2, d2), __fmul_rn(2.0f, dt));
}
// monotone float->uint key (total order preserving)
__device__ __forceinline__ u32 fkey(float f) {
  u32 u = __float_as_uint(f);
  return (u & 0x80000000u) ? ~u : (u | 0x80000000u);
}

// ---- kernels ----

__global__ void k_init_centers(const float* __restrict__ x, float* __restrict__ centers) {
  int i = blockIdx.x * blockDim.x + threadIdx.x;
  if (i >= B * KC * 3) return;
  int b = i / (KC * 3);
  int r = i % (KC * 3);
  centers[i] = x[(size_t)b * N * 3 + r];   // c = x[:, :K, :]
}

__global__ void k_assign(const float* __restrict__ x, const float* __restrict__ centers,
                         unsigned char* __restrict__ cl, int* __restrict__ hist) {
  __shared__ float cx[KC], cy[KC], cz[KC], d2s[KC];
  __shared__ int lh[KC];
  int b = blockIdx.x >> 8;
  int chunk = blockIdx.x & 255;
  int t = threadIdx.x;
  if (t < KC) {
    float a0 = centers[(b * KC + t) * 3 + 0];
    float a1 = centers[(b * KC + t) * 3 + 1];
    float a2 = centers[(b * KC + t) * 3 + 2];
    cx[t] = a0; cy[t] = a1; cz[t] = a2;
    d2s[t] = sq3(a0, a1, a2);
    lh[t] = 0;
  }
  __syncthreads();
  int n = chunk * CHUNK + t;
  size_t xb = ((size_t)b * N + n) * 3;
  float x0 = x[xb], x1 = x[xb + 1], x2 = x[xb + 2];
  float s2 = sq3(x0, x1, x2);
  float best = __int_as_float(0x7f800000);  // +inf
  int bi = 0;
  for (int k = 0; k < KC; ++k) {
    float dt = dot3(x0, x1, x2, cx[k], cy[k], cz[k]);
    float d = distf(s2, d2s[k], dt);
    if (d < best) { best = d; bi = k; }     // first-min tie-break == argmin
  }
  cl[(size_t)b * N + n] = (unsigned char)bi;
  atomicAdd(&lh[bi], 1);
  __syncthreads();
  if (t < KC) hist[((b * NCHUNK) + chunk) * KC + t] = lh[t];
}

__global__ void k_scan_chunks(const int* __restrict__ hist, int* __restrict__ chunkOff,
                              int* __restrict__ totals) {
  int gt = blockIdx.x * blockDim.x + threadIdx.x;
  if (gt >= B * KC) return;
  int b = gt >> 6, k = gt & 63;
  int run = 0;
  for (int c = 0; c < NCHUNK; ++c) {
    int idx = ((b * NCHUNK) + c) * KC + k;
    chunkOff[idx] = run;
    run += hist[idx];
  }
  totals[gt] = run;
}

__global__ void k_batch_prefix(const int* __restrict__ totals, int* __restrict__ kBase) {
  int b = threadIdx.x;
  if (b >= B) return;
  int base = 0;
  for (int k = 0; k < KC; ++k) { kBase[b * KC + k] = base; base += totals[b * KC + k]; }
}

// stable counting-sort scatter: writes point coords grouped by cluster, in
// increasing original index order within each cluster (matches np.add.at order)
__global__ void k_scatter(const float* __restrict__ x, const unsigned char* __restrict__ cl,
                          const int* __restrict__ chunkOff, const int* __restrict__ kBase,
                          float* __restrict__ sortedPts) {
  __shared__ unsigned char lcl[CHUNK];
  int b = blockIdx.x >> 8, chunk = blockIdx.x & 255, t = threadIdx.x;
  int n = chunk * CHUNK + t;
  lcl[t] = cl[(size_t)b * N + n];
  __syncthreads();
  int k = lcl[t];
  int rank = 0;
  for (int j = 0; j < t; ++j) rank += (lcl[j] == k);
  int pos = kBase[b * KC + k] + chunkOff[((b * NCHUNK) + chunk) * KC + k] + rank;
  size_t src = ((size_t)b * N + n) * 3;
  size_t dst = ((size_t)b * N + pos) * 3;
  sortedPts[dst]     = x[src];
  sortedPts[dst + 1] = x[src + 1];
  sortedPts[dst + 2] = x[src + 2];
}

// one block per (b,k): cooperative LDS staging, lane 0 does the strictly
// sequential fp32 sum in original index order (bit-identical to np.add.at)
__global__ void k_sum_divide(const float* __restrict__ sortedPts,
                             const int* __restrict__ kBase, const int* __restrict__ totals,
                             float* __restrict__ centers) {
  __shared__ float buf[3 * SUMCHUNK];
  int gt = blockIdx.x;         // b*KC + k
  int b = gt >> 6;
  int t = threadIdx.x;
  int off = kBase[gt], cnt = totals[gt];
  const float* sp = sortedPts + ((size_t)b * N + off) * 3;
  float sx = 0.f, sy = 0.f, sz = 0.f;
  for (int base = 0; base < cnt; base += SUMCHUNK) {
    int m = min(SUMCHUNK, cnt - base);
    int nf = m * 3;
    for (int i = t; i < nf; i += 256) buf[i] = sp[(size_t)base * 3 + i];
    __syncthreads();
    if (t == 0) {
#pragma unroll 4
      for (int i = 0; i < m; ++i) {
        sx = __fadd_rn(sx, buf[3 * i]);
        sy = __fadd_rn(sy, buf[3 * i + 1]);
        sz = __fadd_rn(sz, buf[3 * i + 2]);
      }
    }
    __syncthreads();
  }
  if (t == 0) {
    float fc = (float)cnt;
    centers[gt * 3 + 0] = __fdiv_rn(sx, fc);
    centers[gt * 3 + 1] = __fdiv_rn(sy, fc);
    centers[gt * 3 + 2] = __fdiv_rn(sz, fc);
  }
}

// exact top-M (smallest distance, lower-index tiebreak) per (b,center)
// via 4-round byte radix-select on monotone keys + exact (key,idx) sort.
__global__ void k_query_topk(const float* __restrict__ x, const float* __restrict__ centers,
                             float* __restrict__ neighbor) {
  __shared__ u32 hist[256];
  __shared__ u64 lessList[M];
  __shared__ u32 eqList[256];
  __shared__ u32 sPrefix;
  __shared__ int sNeed;
  __shared__ int cntLess, cntEq;
  __shared__ float sc0, sc1, sc2, sd2;

  int bk = blockIdx.x;      // b*KC + k
  int b = bk >> 6;
  int t = threadIdx.x;
  if (t == 0) {
    float c0 = centers[bk * 3], c1 = centers[bk * 3 + 1], c2 = centers[bk * 3 + 2];
    sc0 = c0; sc1 = c1; sc2 = c2; sd2 = sq3(c0, c1, c2);
    cntLess = 0; cntEq = 0;
  }
  __syncthreads();
  float c0 = sc0, c1 = sc1, c2 = sc2, d2 = sd2;
  const float* xb = x + (size_t)b * N * 3;

  u32 prefix = 0;
  int need = M;
  for (int r = 3; r >= 0; --r) {
    for (int i = t; i < 256; i += 256) hist[i] = 0;
    __syncthreads();
    int sh = r * 8;
    for (int n = t; n < N; n += 256) {
      float x0 = xb[n * 3], x1 = xb[n * 3 + 1], x2 = xb[n * 3 + 2];
      float d = distf(sq3(x0, x1, x2), d2, dot3(x0, x1, x2, c0, c1, c2));
      u32 key = fkey(d);
      bool ok = (r == 3) || ((key >> (sh + 8)) == (prefix >> (sh + 8)));
      if (ok) atomicAdd(&hist[(key >> sh) & 255u], 1u);
    }
    __syncthreads();
    if (t == 0) {
      int cum = 0;
      for (int bin = 0; bin < 256; ++bin) {
        int c = (int)hist[bin];
        if (cum + c >= need) { sPrefix = prefix | ((u32)bin << sh); sNeed = need - cum; break; }
        cum += c;
      }
    }
    __syncthreads();
    prefix = sPrefix; need = sNeed;
    __syncthreads();
  }
  u32 K128 = prefix;   // exact key of the M-th smallest distance

  for (int n = t; n < N; n += 256) {
    float x0 = xb[n * 3], x1 = xb[n * 3 + 1], x2 = xb[n * 3 + 2];
    float d = distf(sq3(x0, x1, x2), d2, dot3(x0, x1, x2, c0, c1, c2));
    u32 key = fkey(d);
    if (key < K128) {
      int p = atomicAdd(&cntLess, 1);
      if (p < M) lessList[p] = ((u64)key << 32) | (u32)n;   // p < M guaranteed
    } else if (key == K128) {
      int p = atomicAdd(&cntEq, 1);
      if (p < 256) eqList[p] = (u32)n;
    }
  }
  __syncthreads();
  int nl = cntLess;   // < M by construction
  int ne = cntEq;
  for (int i = t; i < M; i += 256) if (i >= nl) lessList[i] = ~0ull;
  for (int i = t; i < 256; i += 256) if (i >= ne) eqList[i] = 0xFFFFFFFFu;
  __syncthreads();

  // bitonic sort lessList[M] ascending by (key, idx)
  for (int ksz = 2; ksz <= M; ksz <<= 1) {
    for (int j = ksz >> 1; j > 0; j >>= 1) {
      if (t < M) {
        int ixj = t ^ j;
        if (ixj > t) {
          u64 a = lessList[t], bb = lessList[ixj];
          bool up = ((t & ksz) == 0);
          if (up ? (a > bb) : (a < bb)) { lessList[t] = bb; lessList[ixj] = a; }
        }
      }
      __syncthreads();
    }
  }
  // bitonic sort eqList[256] ascending by idx
  for (int ksz = 2; ksz <= 256; ksz <<= 1) {
    for (int j = ksz >> 1; j > 0; j >>= 1) {
      int ixj = t ^ j;
      if (ixj > t) {
        u32 a = eqList[t], bb = eqList[ixj];
        bool up = ((t & ksz) == 0);
        if (up ? (a > bb) : (a < bb)) { eqList[t] = bb; eqList[ixj] = a; }
      }
      __syncthreads();
    }
  }

  if (t < M) {
    int idx = (t < nl) ? (int)(lessList[t] & 0xFFFFFFFFu) : (int)eqList[t - nl];
    size_t src = ((size_t)b * N + idx) * 3;
    size_t dst = ((size_t)bk * M + t) * 3;
    neighbor[dst]     = x[src];
    neighbor[dst + 1] = x[src + 1];
    neighbor[dst + 2] = x[src + 2];
  }
}

__global__ void k_fps(const float* __restrict__ neighbor, const int* __restrict__ farthest0,
                      float* __restrict__ out) {
  __shared__ float px[M], py[M], pz[M];
  __shared__ float wv[2];
  __shared__ int wi[2];
  int bg = blockIdx.x;  // b*64 + g
  int b = bg >> 6, g = bg & 63;
  int t = threadIdx.x;  // 128 threads = M
  size_t src = ((size_t)bg * M + t) * 3;
  float mx = neighbor[src], my = neighbor[src + 1], mz = neighbor[src + 2];
  px[t] = mx; py[t] = my; pz[t] = mz;
  int far = farthest0[bg];
  float dist = 1e10f;
  __syncthreads();
  for (int s = 0; s < S; ++s) {
    // record current farthest (scan outputs OLD carry), then update
    if (t == far) {
      size_t dst = ((size_t)b * 4096 + g * 64 + s) * 3;
      out[dst] = mx; out[dst + 1] = my; out[dst + 2] = mz;
    }
    float cx = px[far], cy = py[far], cz = pz[far];
    float dx = __fsub_rn(mx, cx), dy = __fsub_rn(my, cy), dz = __fsub_rn(mz, cz);
    float d = sq3(dx, dy, dz);
    dist = fminf(dist, d);
    float v = dist;
    int i = t;
#pragma unroll
    for (int off = 1; off < 64; off <<= 1) {
      float ov = __shfl_xor(v, off);
      int oi = __shfl_xor(i, off);
      if (ov > v || (ov == v && oi < i)) { v = ov; i = oi; }
    }
    int wid = t >> 6;
    if ((t & 63) == 0) { wv[wid] = v; wi[wid] = i; }
    __syncthreads();
    float v0 = wv[0]; int i0 = wi[0];
    float v1 = wv[1]; int i1 = wi[1];
    far = (v1 > v0 || (v1 == v0 && i1 < i0)) ? i1 : i0;  // first-occurrence argmax
    __syncthreads();
  }
}

__global__ void k_copy_centers(const float* __restrict__ centers, float* __restrict__ out) {
  int i = blockIdx.x * blockDim.x + threadIdx.x;
  if (i < B * KC * 3) out[B * 4096 * 3 + i] = centers[i];
}

extern "C" void kernel_launch(void* const* d_in, const int* in_sizes, int n_in,
                              void* d_out, int out_size, void* d_ws, size_t ws_size,
                              hipStream_t stream) {
  const float* x = (const float*)d_in[0];
  const int* farthest0 = (const int*)d_in[1];
  float* out = (float*)d_out;

  char* w = (char*)d_ws;
  float* centers         = (float*)(w);                         // 6144 B
  int* totals            = (int*)(w + 8192);                    // 2048 B
  int* kBase             = (int*)(w + 16384);                   // 2048 B
  unsigned char* cl      = (unsigned char*)(w + 24576);         // 524288 B
  int* hist              = (int*)(w + 24576 + 524288);          // 524288 B
  int* chunkOff          = (int*)(w + 24576 + 2 * 524288);      // 524288 B
  float* sortedPts       = (float*)(w + 24576 + 3 * 524288);    // 6291456 B
  float* neighbor        = (float*)(w + 24576 + 3 * 524288 + 6291456); // 786432 B
  // total ws use ≈ 8.7 MB

  k_init_centers<<<6, 256, 0, stream>>>(x, centers);
  for (int it = 0; it < NITER; ++it) {
    k_assign<<<B * NCHUNK, 256, 0, stream>>>(x, centers, cl, hist);
    k_scan_chunks<<<2, 256, 0, stream>>>(hist, chunkOff, totals);
    k_batch_prefix<<<1, 64, 0, stream>>>(totals, kBase);
    k_scatter<<<B * NCHUNK, 256, 0, stream>>>(x, cl, chunkOff, kBase, sortedPts);
    k_sum_divide<<<B * KC, 256, 0, stream>>>(sortedPts, kBase, totals, centers);
  }
  k_query_topk<<<B * KC, 256, 0, stream>>>(x, centers, neighbor);
  k_fps<<<B * KC, M, 0, stream>>>(neighbor, farthest0, out);
  k_copy_centers<<<6, 256, 0, stream>>>(centers, out);
}